// Round 7
// baseline (230.609 us; speedup 1.0000x reference)
//
#include <hip/hip_runtime.h>

// ---------------------------------------------------------------------------
// Full counting-sort to a globally bucket-sorted payload, then streaming
// segmented reduction. Buckets = fid >> 7 (128 fragments per bucket).
//   K1 hist:    region k (CHUNK atoms) LDS histogram -> h[k][0..nb) (coalesced)
//   K2a colscan: one wave per bucket b: in-place exclusive scan down column
//                h[*][b] (L2-resident scattered 4B ops), total -> T[b]
//   K2b gscan:  single-block exclusive scan of T -> gstart[0..nb]
//   K3 build:   block k: cursor[b] = gstart[b]+h[k][b] (coalesced row), then
//                per atom: slot = ds_add_rtn(cursor[b]) = FINAL sorted slot;
//                write 32B payload (f, r, fid) once, directly sorted.
//   K4 reduce:  block b: CONTIGUOUS read [gstart[b], gstart[b+1]) -> LDS
//                ds_add_f32 moments -> 3x3 double Cramer solve -> out.
// All large reads coalesced; only K3's writes are scattered (dense, ~1.5x amp).
// Fallback (ws too small): round-1 device-scope atomics.
// ---------------------------------------------------------------------------

#define BSHIFT 7
#define BFRAGS (1 << BSHIFT)
#define NBMAX  2048
#define NACC   13

// ---------------- fallback path (round-1, known correct) -------------------
__global__ void atom_accum_kernel(const float* __restrict__ f_atom,
                                  const float* __restrict__ atom_pos,
                                  const float* __restrict__ T_frag,
                                  const int*   __restrict__ frag_id,
                                  float* __restrict__ acc,
                                  int n_atom, int n_frag) {
    int i = blockIdx.x * blockDim.x + threadIdx.x;
    if (i >= n_atom) return;
    float fx = f_atom[3 * i + 0], fy = f_atom[3 * i + 1], fz = f_atom[3 * i + 2];
    float px = atom_pos[3 * i + 0], py = atom_pos[3 * i + 1], pz = atom_pos[3 * i + 2];
    int fid = frag_id[i];
    float rx = px - T_frag[3 * fid + 0];
    float ry = py - T_frag[3 * fid + 1];
    float rz = pz - T_frag[3 * fid + 2];
    atomicAdd(&acc[0 * n_frag + fid], 1.0f);
    atomicAdd(&acc[1 * n_frag + fid], fx);
    atomicAdd(&acc[2 * n_frag + fid], fy);
    atomicAdd(&acc[3 * n_frag + fid], fz);
    atomicAdd(&acc[4 * n_frag + fid], ry * fz - rz * fy);
    atomicAdd(&acc[5 * n_frag + fid], rz * fx - rx * fz);
    atomicAdd(&acc[6 * n_frag + fid], rx * fy - ry * fx);
    atomicAdd(&acc[7 * n_frag + fid], rx * rx);
    atomicAdd(&acc[8 * n_frag + fid], ry * ry);
    atomicAdd(&acc[9 * n_frag + fid], rz * rz);
    atomicAdd(&acc[10 * n_frag + fid], rx * ry);
    atomicAdd(&acc[11 * n_frag + fid], rx * rz);
    atomicAdd(&acc[12 * n_frag + fid], ry * rz);
}

__device__ __forceinline__ void solve_frag(const float s[NACC], int fs,
                                           float* vout, float* oout) {
    float inv_cnt = 1.0f / fmaxf(s[0], 1.0f);
    vout[0] = s[1] * inv_cnt;
    vout[1] = s[2] * inv_cnt;
    vout[2] = s[3] * inv_cnt;

    double sxx = (double)s[7], syy = (double)s[8], szz = (double)s[9];
    double sxy = (double)s[10], sxz = (double)s[11], syz = (double)s[12];
    const double eps = 1e-4;
    double d = sxx + syy + szz;
    double a00 = d - sxx + eps, a11 = d - syy + eps, a22 = d - szz + eps;
    double a01 = -sxy, a02 = -sxz, a12 = -syz;

    double c00 = a11 * a22 - a12 * a12;
    double c01 = a02 * a12 - a01 * a22;
    double c02 = a01 * a12 - a02 * a11;
    double det = a00 * c00 + a01 * c01 + a02 * c02;
    double inv_det = (det != 0.0) ? 1.0 / det : 0.0;
    double c11 = a00 * a22 - a02 * a02;
    double c12 = a01 * a02 - a00 * a12;
    double c22 = a00 * a11 - a01 * a01;

    double tx = (double)s[4], ty = (double)s[5], tz = (double)s[6];
    if (fs <= 1) {
        oout[0] = 0.0f; oout[1] = 0.0f; oout[2] = 0.0f;
    } else {
        oout[0] = (float)((c00 * tx + c01 * ty + c02 * tz) * inv_det);
        oout[1] = (float)((c01 * tx + c11 * ty + c12 * tz) * inv_det);
        oout[2] = (float)((c02 * tx + c12 * ty + c22 * tz) * inv_det);
    }
}

__global__ void finalize_accum_kernel(const float* __restrict__ acc,
                                      const int* __restrict__ frag_sizes,
                                      float* __restrict__ out, int n_frag) {
    int i = blockIdx.x * blockDim.x + threadIdx.x;
    if (i >= n_frag) return;
    float s[NACC];
#pragma unroll
    for (int c = 0; c < NACC; ++c) s[c] = acc[(size_t)c * n_frag + i];
    float v[3], o[3];
    solve_frag(s, frag_sizes[i], v, o);
    out[3 * i + 0] = v[0]; out[3 * i + 1] = v[1]; out[3 * i + 2] = v[2];
    float* om = out + 3 * (size_t)n_frag;
    om[3 * i + 0] = o[0]; om[3 * i + 1] = o[1]; om[3 * i + 2] = o[2];
}

// ---------------- sorted path ----------------------------------------------

__global__ __launch_bounds__(512)
void hist_kernel(const int* __restrict__ frag_id, unsigned* __restrict__ h,
                 int n_atom, int nb, int cshift) {
    __shared__ unsigned hh[NBMAX];
    int tid = threadIdx.x;
    for (int t = tid; t < nb; t += 512) hh[t] = 0;
    __syncthreads();
    int c0 = blockIdx.x << cshift;
    int cend = min(c0 + (1 << cshift), n_atom);
    for (int i = c0 + tid; i < cend; i += 512)
        atomicAdd(&hh[frag_id[i] >> BSHIFT], 1u);
    __syncthreads();
    size_t row = (size_t)blockIdx.x * nb;
    for (int t = tid; t < nb; t += 512) h[row + t] = hh[t];
}

// One wave per bucket: in-place exclusive scan down column h[*][b]; total->T[b]
__global__ void colscan_kernel(unsigned* __restrict__ h, unsigned* __restrict__ T,
                               int nb, int nreg) {
    int wid = (blockIdx.x * blockDim.x + threadIdx.x) >> 6;
    int lane = threadIdx.x & 63;
    if (wid >= nb) return;
    unsigned run = 0;
    for (int k0 = 0; k0 < nreg; k0 += 64) {
        int k = k0 + lane;
        unsigned v = (k < nreg) ? h[(size_t)k * nb + wid] : 0u;
        unsigned incl = v;
#pragma unroll
        for (int o = 1; o < 64; o <<= 1) {
            unsigned x = __shfl_up(incl, o);
            if (lane >= o) incl += x;
        }
        if (k < nreg) h[(size_t)k * nb + wid] = run + (incl - v);
        run += __shfl(incl, 63);
    }
    if (lane == 0) T[wid] = run;
}

// Single-block exclusive scan of T[0..nb) -> gstart[0..nb]
__global__ __launch_bounds__(1024)
void gscan_kernel(const unsigned* __restrict__ T, unsigned* __restrict__ gstart,
                  int nb) {
    __shared__ unsigned s[1024];
    int t = threadIdx.x;
    unsigned v0 = (2 * t < nb) ? T[2 * t] : 0u;
    unsigned v1 = (2 * t + 1 < nb) ? T[2 * t + 1] : 0u;
    unsigned p = v0 + v1;
    s[t] = p;
    __syncthreads();
    for (int o = 1; o < 1024; o <<= 1) {
        unsigned x = (t >= o) ? s[t - o] : 0u;
        __syncthreads();
        s[t] += x;
        __syncthreads();
    }
    unsigned excl = s[t] - p;
    if (2 * t < nb) gstart[2 * t] = excl;
    if (2 * t + 1 < nb) gstart[2 * t + 1] = excl + v0;
    if (t == 1023) gstart[nb] = s[1023];
}

__global__ __launch_bounds__(512)
void build_kernel(const float* __restrict__ f_atom,
                  const float* __restrict__ atom_pos,
                  const float* __restrict__ T_frag,
                  const int* __restrict__ frag_id,
                  const unsigned* __restrict__ h,
                  const unsigned* __restrict__ gstart,
                  float* __restrict__ payload,
                  int n_atom, int nb, int cshift) {
    __shared__ unsigned cursor[NBMAX];
    int tid = threadIdx.x;
    size_t row = (size_t)blockIdx.x * nb;
    for (int t = tid; t < nb; t += 512) cursor[t] = gstart[t] + h[row + t];
    __syncthreads();
    int c0 = blockIdx.x << cshift;
    int cend = min(c0 + (1 << cshift), n_atom);
    for (int i = c0 + tid; i < cend; i += 512) {
        int fid = frag_id[i];
        int b = fid >> BSHIFT;
        unsigned dst = atomicAdd(&cursor[b], 1u);   // ds_add_rtn_u32: final slot
        float fx = f_atom[3 * i + 0], fy = f_atom[3 * i + 1], fz = f_atom[3 * i + 2];
        float rx = atom_pos[3 * i + 0] - T_frag[3 * fid + 0];
        float ry = atom_pos[3 * i + 1] - T_frag[3 * fid + 1];
        float rz = atom_pos[3 * i + 2] - T_frag[3 * fid + 2];
        float4* p = (float4*)(payload + (size_t)dst * 8);
        p[0] = make_float4(fx, fy, fz, __int_as_float(fid));
        p[1] = make_float4(rx, ry, rz, 0.0f);
    }
}

__global__ __launch_bounds__(512)
void reduce_kernel(const float* __restrict__ payload,
                   const unsigned* __restrict__ gstart,
                   const int* __restrict__ frag_sizes,
                   float* __restrict__ out, int n_frag, int nb) {
    __shared__ float acc[BFRAGS * NACC];   // 6656 B
    int b = blockIdx.x;
    int tid = threadIdx.x;
    for (int t = tid; t < BFRAGS * NACC; t += 512) acc[t] = 0.0f;
    __syncthreads();

    unsigned s0 = gstart[b], s1 = gstart[b + 1];
    for (unsigned s = s0 + tid; s < s1; s += 512) {
        const float4* p = (const float4*)(payload + (size_t)s * 8);
        float4 a = p[0];
        float4 c = p[1];
        float fx = a.x, fy = a.y, fz = a.z;
        int fid = __float_as_int(a.w);
        float rx = c.x, ry = c.y, rz = c.z;
        float* A = &acc[(fid - (b << BSHIFT)) * NACC];
        unsafeAtomicAdd(&A[0], 1.0f);
        unsafeAtomicAdd(&A[1], fx);
        unsafeAtomicAdd(&A[2], fy);
        unsafeAtomicAdd(&A[3], fz);
        unsafeAtomicAdd(&A[4], ry * fz - rz * fy);
        unsafeAtomicAdd(&A[5], rz * fx - rx * fz);
        unsafeAtomicAdd(&A[6], rx * fy - ry * fx);
        unsafeAtomicAdd(&A[7], rx * rx);
        unsafeAtomicAdd(&A[8], ry * ry);
        unsafeAtomicAdd(&A[9], rz * rz);
        unsafeAtomicAdd(&A[10], rx * ry);
        unsafeAtomicAdd(&A[11], rx * rz);
        unsafeAtomicAdd(&A[12], ry * rz);
    }
    __syncthreads();

    int fid0 = b << BSHIFT;
    for (int lf = tid; lf < BFRAGS; lf += 512) {
        int fid = fid0 + lf;
        if (fid >= n_frag) continue;
        float sv[NACC];
#pragma unroll
        for (int c = 0; c < NACC; ++c) sv[c] = acc[lf * NACC + c];
        float v[3], o[3];
        solve_frag(sv, frag_sizes[fid], v, o);
        out[3 * fid + 0] = v[0]; out[3 * fid + 1] = v[1]; out[3 * fid + 2] = v[2];
        float* om = out + 3 * (size_t)n_frag;
        om[3 * fid + 0] = o[0]; om[3 * fid + 1] = o[1]; om[3 * fid + 2] = o[2];
    }
}

// ---------------------------------------------------------------------------

static inline size_t pad256(size_t x) { return (x + 255) & ~(size_t)255; }

extern "C" void kernel_launch(void* const* d_in, const int* in_sizes, int n_in,
                              void* d_out, int out_size, void* d_ws, size_t ws_size,
                              hipStream_t stream) {
    const float* f_atom   = (const float*)d_in[0];
    const float* atom_pos = (const float*)d_in[1];
    const float* T_frag   = (const float*)d_in[2];
    const int*   frag_id  = (const int*)d_in[3];
    const int*   frag_sizes = (const int*)d_in[5];

    int n_atom = in_sizes[0] / 3;
    int n_frag = in_sizes[2] / 3;
    int nb = (n_frag + BFRAGS - 1) >> BSHIFT;

    // pick chunk size: prefer 2048-atom regions (better K3 occupancy), fall
    // back to 4096 if the h matrix doesn't fit, else atomic path.
    int cshift = -1;
    size_t h_bytes = 0, ctl_bytes = 0;
    size_t payload_bytes = (size_t)n_atom * 8 * sizeof(float);
    for (int cs = 11; cs <= 12 && cshift < 0; ++cs) {
        int nreg = (n_atom + (1 << cs) - 1) >> cs;
        size_t hb = pad256((size_t)nreg * nb * sizeof(unsigned));
        size_t cb = pad256(((size_t)nb + (size_t)nb + 1) * sizeof(unsigned));
        if (nb <= NBMAX && hb + cb + payload_bytes <= ws_size) {
            cshift = cs; h_bytes = hb; ctl_bytes = cb;
        }
    }

    if (cshift >= 0) {
        int nreg = (n_atom + (1 << cshift) - 1) >> cshift;
        unsigned* h      = (unsigned*)d_ws;
        unsigned* T      = (unsigned*)((char*)d_ws + h_bytes);
        unsigned* gstart = T + nb;
        float* payload   = (float*)((char*)d_ws + h_bytes + ctl_bytes);

        hist_kernel<<<nreg, 512, 0, stream>>>(frag_id, h, n_atom, nb, cshift);
        int cs_blocks = (nb * 64 + 255) / 256;   // one wave per bucket
        colscan_kernel<<<cs_blocks, 256, 0, stream>>>(h, T, nb, nreg);
        gscan_kernel<<<1, 1024, 0, stream>>>(T, gstart, nb);
        build_kernel<<<nreg, 512, 0, stream>>>(f_atom, atom_pos, T_frag, frag_id,
                                               h, gstart, payload, n_atom, nb, cshift);
        reduce_kernel<<<nb, 512, 0, stream>>>(payload, gstart, frag_sizes,
                                              (float*)d_out, n_frag, nb);
    } else {
        // fallback: direct device-scope atomic accumulation
        float* acc = (float*)d_ws;
        hipMemsetAsync(acc, 0, (size_t)NACC * n_frag * sizeof(float), stream);
        int threads = 256;
        atom_accum_kernel<<<(n_atom + threads - 1) / threads, threads, 0, stream>>>(
            f_atom, atom_pos, T_frag, frag_id, acc, n_atom, n_frag);
        finalize_accum_kernel<<<(n_frag + threads - 1) / threads, threads, 0, stream>>>(
            acc, frag_sizes, (float*)d_out, n_frag);
    }
}

// Round 8
// 111.311 us; speedup vs baseline: 2.0718x; 2.0718x over previous
//
#include <hip/hip_runtime.h>

// ---------------------------------------------------------------------------
// Full counting-sort to a globally bucket-sorted payload, then a reduction
// with ZERO LDS float atomics:
//   K1 hist:    region k (2048 atoms) LDS histogram -> h[k][0..nb) (coalesced)
//   K2a colscan: one wave per bucket b: exclusive scan down column h[*][b]
//   K2b gscan:  single-block exclusive scan of totals -> gstart[0..nb]
//   K3 build:   block k: cursor = gstart + h-row; slot = ds_add_rtn -> write
//               32B payload (f, r, fid) once, globally bucket-sorted.
//   K4 reduce:  block b: phase A: coalesced payload -> regs, 1 int ds_add_rtn
//               rank per atom, scan counts, stage fragment-sorted into LDS.
//               phase B: one THREAD per fragment: contiguous LDS range ->
//               13 register moments -> 3x3 double Cramer solve -> out.
//               (no ds_add_f32 anywhere - r7's 155us floor was same-address
//                LDS float-atomic serialization, invariant across r5/r6/r7)
// Fallbacks: bucket overflow (n>CAP) -> per-block LDS-atomic path;
//            ws too small -> round-1 device-scope atomics.
// ---------------------------------------------------------------------------

#define BSHIFT 7
#define BFRAGS (1 << BSHIFT)
#define NBMAX  2048
#define NACC   13
#define CAP    1536            // 3 * 512; LDS stage = 48 KB

// ---------------- fallback path (round-1, known correct) -------------------
__global__ void atom_accum_kernel(const float* __restrict__ f_atom,
                                  const float* __restrict__ atom_pos,
                                  const float* __restrict__ T_frag,
                                  const int*   __restrict__ frag_id,
                                  float* __restrict__ acc,
                                  int n_atom, int n_frag) {
    int i = blockIdx.x * blockDim.x + threadIdx.x;
    if (i >= n_atom) return;
    float fx = f_atom[3 * i + 0], fy = f_atom[3 * i + 1], fz = f_atom[3 * i + 2];
    float px = atom_pos[3 * i + 0], py = atom_pos[3 * i + 1], pz = atom_pos[3 * i + 2];
    int fid = frag_id[i];
    float rx = px - T_frag[3 * fid + 0];
    float ry = py - T_frag[3 * fid + 1];
    float rz = pz - T_frag[3 * fid + 2];
    atomicAdd(&acc[0 * n_frag + fid], 1.0f);
    atomicAdd(&acc[1 * n_frag + fid], fx);
    atomicAdd(&acc[2 * n_frag + fid], fy);
    atomicAdd(&acc[3 * n_frag + fid], fz);
    atomicAdd(&acc[4 * n_frag + fid], ry * fz - rz * fy);
    atomicAdd(&acc[5 * n_frag + fid], rz * fx - rx * fz);
    atomicAdd(&acc[6 * n_frag + fid], rx * fy - ry * fx);
    atomicAdd(&acc[7 * n_frag + fid], rx * rx);
    atomicAdd(&acc[8 * n_frag + fid], ry * ry);
    atomicAdd(&acc[9 * n_frag + fid], rz * rz);
    atomicAdd(&acc[10 * n_frag + fid], rx * ry);
    atomicAdd(&acc[11 * n_frag + fid], rx * rz);
    atomicAdd(&acc[12 * n_frag + fid], ry * rz);
}

__device__ __forceinline__ void solve_frag(const float s[NACC], int fs,
                                           float* vout, float* oout) {
    float inv_cnt = 1.0f / fmaxf(s[0], 1.0f);
    vout[0] = s[1] * inv_cnt;
    vout[1] = s[2] * inv_cnt;
    vout[2] = s[3] * inv_cnt;

    double sxx = (double)s[7], syy = (double)s[8], szz = (double)s[9];
    double sxy = (double)s[10], sxz = (double)s[11], syz = (double)s[12];
    const double eps = 1e-4;
    double d = sxx + syy + szz;
    double a00 = d - sxx + eps, a11 = d - syy + eps, a22 = d - szz + eps;
    double a01 = -sxy, a02 = -sxz, a12 = -syz;

    double c00 = a11 * a22 - a12 * a12;
    double c01 = a02 * a12 - a01 * a22;
    double c02 = a01 * a12 - a02 * a11;
    double det = a00 * c00 + a01 * c01 + a02 * c02;
    double inv_det = (det != 0.0) ? 1.0 / det : 0.0;
    double c11 = a00 * a22 - a02 * a02;
    double c12 = a01 * a02 - a00 * a12;
    double c22 = a00 * a11 - a01 * a01;

    double tx = (double)s[4], ty = (double)s[5], tz = (double)s[6];
    if (fs <= 1) {
        oout[0] = 0.0f; oout[1] = 0.0f; oout[2] = 0.0f;
    } else {
        oout[0] = (float)((c00 * tx + c01 * ty + c02 * tz) * inv_det);
        oout[1] = (float)((c01 * tx + c11 * ty + c12 * tz) * inv_det);
        oout[2] = (float)((c02 * tx + c12 * ty + c22 * tz) * inv_det);
    }
}

__global__ void finalize_accum_kernel(const float* __restrict__ acc,
                                      const int* __restrict__ frag_sizes,
                                      float* __restrict__ out, int n_frag) {
    int i = blockIdx.x * blockDim.x + threadIdx.x;
    if (i >= n_frag) return;
    float s[NACC];
#pragma unroll
    for (int c = 0; c < NACC; ++c) s[c] = acc[(size_t)c * n_frag + i];
    float v[3], o[3];
    solve_frag(s, frag_sizes[i], v, o);
    out[3 * i + 0] = v[0]; out[3 * i + 1] = v[1]; out[3 * i + 2] = v[2];
    float* om = out + 3 * (size_t)n_frag;
    om[3 * i + 0] = o[0]; om[3 * i + 1] = o[1]; om[3 * i + 2] = o[2];
}

// ---------------- sorted path ----------------------------------------------

__global__ __launch_bounds__(512)
void hist_kernel(const int* __restrict__ frag_id, unsigned* __restrict__ h,
                 int n_atom, int nb, int cshift) {
    __shared__ unsigned hh[NBMAX];
    int tid = threadIdx.x;
    for (int t = tid; t < nb; t += 512) hh[t] = 0;
    __syncthreads();
    int c0 = blockIdx.x << cshift;
    int cend = min(c0 + (1 << cshift), n_atom);
    for (int i = c0 + tid; i < cend; i += 512)
        atomicAdd(&hh[frag_id[i] >> BSHIFT], 1u);
    __syncthreads();
    size_t row = (size_t)blockIdx.x * nb;
    for (int t = tid; t < nb; t += 512) h[row + t] = hh[t];
}

__global__ void colscan_kernel(unsigned* __restrict__ h, unsigned* __restrict__ T,
                               int nb, int nreg) {
    int wid = (blockIdx.x * blockDim.x + threadIdx.x) >> 6;
    int lane = threadIdx.x & 63;
    if (wid >= nb) return;
    unsigned run = 0;
    for (int k0 = 0; k0 < nreg; k0 += 64) {
        int k = k0 + lane;
        unsigned v = (k < nreg) ? h[(size_t)k * nb + wid] : 0u;
        unsigned incl = v;
#pragma unroll
        for (int o = 1; o < 64; o <<= 1) {
            unsigned x = __shfl_up(incl, o);
            if (lane >= o) incl += x;
        }
        if (k < nreg) h[(size_t)k * nb + wid] = run + (incl - v);
        run += __shfl(incl, 63);
    }
    if (lane == 0) T[wid] = run;
}

__global__ __launch_bounds__(1024)
void gscan_kernel(const unsigned* __restrict__ T, unsigned* __restrict__ gstart,
                  int nb) {
    __shared__ unsigned s[1024];
    int t = threadIdx.x;
    unsigned v0 = (2 * t < nb) ? T[2 * t] : 0u;
    unsigned v1 = (2 * t + 1 < nb) ? T[2 * t + 1] : 0u;
    unsigned p = v0 + v1;
    s[t] = p;
    __syncthreads();
    for (int o = 1; o < 1024; o <<= 1) {
        unsigned x = (t >= o) ? s[t - o] : 0u;
        __syncthreads();
        s[t] += x;
        __syncthreads();
    }
    unsigned excl = s[t] - p;
    if (2 * t < nb) gstart[2 * t] = excl;
    if (2 * t + 1 < nb) gstart[2 * t + 1] = excl + v0;
    if (t == 1023) gstart[nb] = s[1023];
}

__global__ __launch_bounds__(512)
void build_kernel(const float* __restrict__ f_atom,
                  const float* __restrict__ atom_pos,
                  const float* __restrict__ T_frag,
                  const int* __restrict__ frag_id,
                  const unsigned* __restrict__ h,
                  const unsigned* __restrict__ gstart,
                  float* __restrict__ payload,
                  int n_atom, int nb, int cshift) {
    __shared__ unsigned cursor[NBMAX];
    int tid = threadIdx.x;
    size_t row = (size_t)blockIdx.x * nb;
    for (int t = tid; t < nb; t += 512) cursor[t] = gstart[t] + h[row + t];
    __syncthreads();
    int c0 = blockIdx.x << cshift;
    int cend = min(c0 + (1 << cshift), n_atom);
    for (int i = c0 + tid; i < cend; i += 512) {
        int fid = frag_id[i];
        int b = fid >> BSHIFT;
        unsigned dst = atomicAdd(&cursor[b], 1u);   // ds_add_rtn_u32: final slot
        float fx = f_atom[3 * i + 0], fy = f_atom[3 * i + 1], fz = f_atom[3 * i + 2];
        float rx = atom_pos[3 * i + 0] - T_frag[3 * fid + 0];
        float ry = atom_pos[3 * i + 1] - T_frag[3 * fid + 1];
        float rz = atom_pos[3 * i + 2] - T_frag[3 * fid + 2];
        float4* p = (float4*)(payload + (size_t)dst * 8);
        p[0] = make_float4(fx, fy, fz, __int_as_float(fid));
        p[1] = make_float4(rx, ry, rz, 0.0f);
    }
}

__global__ __launch_bounds__(512)
void reduce_kernel(const float* __restrict__ payload,
                   const unsigned* __restrict__ gstart,
                   const int* __restrict__ frag_sizes,
                   float* __restrict__ out, int n_frag, int nb) {
    __shared__ float stage[CAP * 8];          // 48 KB: fragment-sorted payload
    __shared__ unsigned cnt[BFRAGS];
    __shared__ unsigned sc[BFRAGS];
    __shared__ unsigned fstart[BFRAGS + 1];

    int b = blockIdx.x;
    int tid = threadIdx.x;
    unsigned s0 = gstart[b], s1 = gstart[b + 1];
    unsigned n = s1 - s0;

    if (tid < BFRAGS) cnt[tid] = 0;
    __syncthreads();

    if (n <= CAP) {   // block-uniform branch
        // ---- phase A: coalesced load -> regs; rank via ONE int ds_add_rtn
        float4 p0j[3], p1j[3];
        unsigned rankj[3]; int lfj[3]; bool actj[3];
#pragma unroll
        for (int j = 0; j < 3; ++j) {
            unsigned s = s0 + (unsigned)tid + (unsigned)j * 512u;
            actj[j] = (s < s1);
            lfj[j] = 0; rankj[j] = 0;
            if (actj[j]) {
                const float4* p = (const float4*)(payload + (size_t)s * 8);
                p0j[j] = p[0];
                p1j[j] = p[1];
                lfj[j] = __float_as_int(p0j[j].w) & (BFRAGS - 1);
                rankj[j] = atomicAdd(&cnt[lfj[j]], 1u);   // ds_add_rtn_u32
            }
        }
        __syncthreads();

        // ---- scan cnt[128] -> fstart (exclusive)
        if (tid < BFRAGS) sc[tid] = cnt[tid];
        __syncthreads();
        for (int o = 1; o < BFRAGS; o <<= 1) {
            unsigned x = 0;
            if (tid < BFRAGS && tid >= o) x = sc[tid - o];
            __syncthreads();
            if (tid < BFRAGS) sc[tid] += x;
            __syncthreads();
        }
        if (tid < BFRAGS) fstart[tid] = sc[tid] - cnt[tid];
        if (tid == 0) fstart[BFRAGS] = n;
        __syncthreads();

        // ---- stage fragment-sorted into LDS (plain writes, no atomics)
#pragma unroll
        for (int j = 0; j < 3; ++j) {
            if (actj[j]) {
                unsigned slot = fstart[lfj[j]] + rankj[j];
                float4* d = (float4*)&stage[(size_t)slot * 8];
                d[0] = p0j[j];
                d[1] = p1j[j];
            }
        }
        __syncthreads();

        // ---- phase B: one thread per fragment, register moments
        if (tid < BFRAGS) {
            int fid = (b << BSHIFT) + tid;
            if (fid < n_frag) {
                float m0 = 0.f, m1 = 0.f, m2 = 0.f, m3 = 0.f, m4 = 0.f,
                      m5 = 0.f, m6 = 0.f, m7 = 0.f, m8 = 0.f, m9 = 0.f,
                      m10 = 0.f, m11 = 0.f, m12 = 0.f;
                unsigned e0 = fstart[tid], e1 = fstart[tid + 1];
                for (unsigned j = e0; j < e1; ++j) {
                    const float4* q = (const float4*)&stage[(size_t)j * 8];
                    float4 a = q[0];
                    float4 c = q[1];
                    float fx = a.x, fy = a.y, fz = a.z;
                    float rx = c.x, ry = c.y, rz = c.z;
                    m0 += 1.0f;
                    m1 += fx; m2 += fy; m3 += fz;
                    m4 += ry * fz - rz * fy;
                    m5 += rz * fx - rx * fz;
                    m6 += rx * fy - ry * fx;
                    m7 += rx * rx; m8 += ry * ry; m9 += rz * rz;
                    m10 += rx * ry; m11 += rx * rz; m12 += ry * rz;
                }
                float sv[NACC] = {m0, m1, m2, m3, m4, m5, m6,
                                  m7, m8, m9, m10, m11, m12};
                float v[3], o[3];
                solve_frag(sv, frag_sizes[fid], v, o);
                out[3 * fid + 0] = v[0];
                out[3 * fid + 1] = v[1];
                out[3 * fid + 2] = v[2];
                float* om = out + 3 * (size_t)n_frag;
                om[3 * fid + 0] = o[0];
                om[3 * fid + 1] = o[1];
                om[3 * fid + 2] = o[2];
            }
        }
    } else {
        // ---- overflow fallback (n > CAP): LDS float-atomic path (r7)
        float* acc = stage;    // reuse
        for (int t = tid; t < BFRAGS * NACC; t += 512) acc[t] = 0.0f;
        __syncthreads();
        for (unsigned s = s0 + tid; s < s1; s += 512) {
            const float4* p = (const float4*)(payload + (size_t)s * 8);
            float4 a = p[0];
            float4 c = p[1];
            float fx = a.x, fy = a.y, fz = a.z;
            int fid = __float_as_int(a.w);
            float rx = c.x, ry = c.y, rz = c.z;
            float* A = &acc[(fid - (b << BSHIFT)) * NACC];
            atomicAdd(&A[0], 1.0f);
            atomicAdd(&A[1], fx);
            atomicAdd(&A[2], fy);
            atomicAdd(&A[3], fz);
            atomicAdd(&A[4], ry * fz - rz * fy);
            atomicAdd(&A[5], rz * fx - rx * fz);
            atomicAdd(&A[6], rx * fy - ry * fx);
            atomicAdd(&A[7], rx * rx);
            atomicAdd(&A[8], ry * ry);
            atomicAdd(&A[9], rz * rz);
            atomicAdd(&A[10], rx * ry);
            atomicAdd(&A[11], rx * rz);
            atomicAdd(&A[12], ry * rz);
        }
        __syncthreads();
        if (tid < BFRAGS) {
            int fid = (b << BSHIFT) + tid;
            if (fid < n_frag) {
                float sv[NACC];
#pragma unroll
                for (int c = 0; c < NACC; ++c) sv[c] = acc[tid * NACC + c];
                float v[3], o[3];
                solve_frag(sv, frag_sizes[fid], v, o);
                out[3 * fid + 0] = v[0];
                out[3 * fid + 1] = v[1];
                out[3 * fid + 2] = v[2];
                float* om = out + 3 * (size_t)n_frag;
                om[3 * fid + 0] = o[0];
                om[3 * fid + 1] = o[1];
                om[3 * fid + 2] = o[2];
            }
        }
    }
}

// ---------------------------------------------------------------------------

static inline size_t pad256(size_t x) { return (x + 255) & ~(size_t)255; }

extern "C" void kernel_launch(void* const* d_in, const int* in_sizes, int n_in,
                              void* d_out, int out_size, void* d_ws, size_t ws_size,
                              hipStream_t stream) {
    const float* f_atom   = (const float*)d_in[0];
    const float* atom_pos = (const float*)d_in[1];
    const float* T_frag   = (const float*)d_in[2];
    const int*   frag_id  = (const int*)d_in[3];
    const int*   frag_sizes = (const int*)d_in[5];

    int n_atom = in_sizes[0] / 3;
    int n_frag = in_sizes[2] / 3;
    int nb = (n_frag + BFRAGS - 1) >> BSHIFT;

    int cshift = -1;
    size_t h_bytes = 0, ctl_bytes = 0;
    size_t payload_bytes = (size_t)n_atom * 8 * sizeof(float);
    for (int cs = 11; cs <= 12 && cshift < 0; ++cs) {
        int nreg = (n_atom + (1 << cs) - 1) >> cs;
        size_t hb = pad256((size_t)nreg * nb * sizeof(unsigned));
        size_t cb = pad256(((size_t)nb + (size_t)nb + 1) * sizeof(unsigned));
        if (nb <= NBMAX && hb + cb + payload_bytes <= ws_size) {
            cshift = cs; h_bytes = hb; ctl_bytes = cb;
        }
    }

    if (cshift >= 0) {
        int nreg = (n_atom + (1 << cshift) - 1) >> cshift;
        unsigned* h      = (unsigned*)d_ws;
        unsigned* T      = (unsigned*)((char*)d_ws + h_bytes);
        unsigned* gstart = T + nb;
        float* payload   = (float*)((char*)d_ws + h_bytes + ctl_bytes);

        hist_kernel<<<nreg, 512, 0, stream>>>(frag_id, h, n_atom, nb, cshift);
        int cs_blocks = (nb * 64 + 255) / 256;
        colscan_kernel<<<cs_blocks, 256, 0, stream>>>(h, T, nb, nreg);
        gscan_kernel<<<1, 1024, 0, stream>>>(T, gstart, nb);
        build_kernel<<<nreg, 512, 0, stream>>>(f_atom, atom_pos, T_frag, frag_id,
                                               h, gstart, payload, n_atom, nb, cshift);
        reduce_kernel<<<nb, 512, 0, stream>>>(payload, gstart, frag_sizes,
                                              (float*)d_out, n_frag, nb);
    } else {
        float* acc = (float*)d_ws;
        hipMemsetAsync(acc, 0, (size_t)NACC * n_frag * sizeof(float), stream);
        int threads = 256;
        atom_accum_kernel<<<(n_atom + threads - 1) / threads, threads, 0, stream>>>(
            f_atom, atom_pos, T_frag, frag_id, acc, n_atom, n_frag);
        finalize_accum_kernel<<<(n_frag + threads - 1) / threads, threads, 0, stream>>>(
            acc, frag_sizes, (float*)d_out, n_frag);
    }
}